// Round 1
// baseline (4280.296 us; speedup 1.0000x reference)
//
#include <hip/hip_runtime.h>
#include <hip/hip_bf16.h>

// ---------------------------------------------------------------------------
// GCN-VGAE encoder, f32 end-to-end.
//   deg/dinv -> [GEMM -> self-init -> edge-scatter -> BN-stats -> BN+ReLU] x2
//            -> self-init -> edge-scatter -> split GEMM (mu | logvar) -> d_out
// Aggregation uses f32 atomics (round-1 baseline; CSR planned if dominant).
// ---------------------------------------------------------------------------

#define D_H 128

__global__ __launch_bounds__(256)
void deg_count(const int* __restrict__ ei, int* __restrict__ cnt, int E_) {
    int e = blockIdx.x * 256 + threadIdx.x;
    if (e < E_) atomicAdd(&cnt[ei[E_ + e]], 1);   // row 1 = dst
}

__global__ __launch_bounds__(256)
void make_dinv(const int* __restrict__ cnt, float* __restrict__ dinv, int n) {
    int i = blockIdx.x * 256 + threadIdx.x;
    if (i < n) dinv[i] = rsqrtf((float)cnt[i] + 1.0f);
}

// Y = X @ W  (K=128). SPLIT: W = [Wa|Wb] (each 128x64), Ya/Yb are N x 64.
// Block: 256 threads -> 32 rows x 128 cols, 4x4 accumulators per thread.
template<bool SPLIT>
__global__ __launch_bounds__(256)
void gemm128(const float* __restrict__ X, const float* __restrict__ Wa,
             const float* __restrict__ Wb, float* __restrict__ Ya,
             float* __restrict__ Yb, int nRows) {
    __shared__ float xs[32][128];
    const int tid = threadIdx.x;
    const int row0 = blockIdx.x * 32;

    // stage 32x128 x-tile (row-major), coalesced float4
    #pragma unroll
    for (int q = 0; q < 4; ++q) {
        int flat = (q * 256 + tid) * 4;         // 0..4095
        int r = flat >> 7, k = flat & 127;
        float4 v = make_float4(0.f, 0.f, 0.f, 0.f);
        if (row0 + r < nRows)
            v = *(const float4*)(X + (size_t)(row0 + r) * 128 + k);
        *(float4*)&xs[r][k] = v;
    }
    __syncthreads();

    const int tx = tid & 31, ty = tid >> 5;
    const int c0 = tx * 4, r0 = ty * 4;
    float acc[4][4] = {};

    for (int k = 0; k < 128; k += 4) {
        float xv[4][4];
        #pragma unroll
        for (int i = 0; i < 4; ++i)
            *(float4*)xv[i] = *(const float4*)&xs[r0 + i][k];
        #pragma unroll
        for (int j = 0; j < 4; ++j) {
            int kk = k + j;
            float4 wv;
            if (!SPLIT) {
                wv = *(const float4*)(Wa + kk * 128 + c0);
            } else {
                wv = (c0 < 64) ? *(const float4*)(Wa + kk * 64 + c0)
                               : *(const float4*)(Wb + kk * 64 + (c0 - 64));
            }
            #pragma unroll
            for (int i = 0; i < 4; ++i) {
                acc[i][0] += xv[i][j] * wv.x;
                acc[i][1] += xv[i][j] * wv.y;
                acc[i][2] += xv[i][j] * wv.z;
                acc[i][3] += xv[i][j] * wv.w;
            }
        }
    }

    #pragma unroll
    for (int i = 0; i < 4; ++i) {
        int r = row0 + r0 + i;
        if (r >= nRows) continue;
        float4 o = make_float4(acc[i][0], acc[i][1], acc[i][2], acc[i][3]);
        if (!SPLIT) {
            *(float4*)(Ya + (size_t)r * 128 + c0) = o;
        } else if (c0 < 64) {
            *(float4*)(Ya + (size_t)r * 64 + c0) = o;
        } else {
            *(float4*)(Yb + (size_t)r * 64 + (c0 - 64)) = o;
        }
    }
}

// O[r,:] = M[r,:] * dinv[r]^2   (self-loop term, also zero-replaces poison)
__global__ __launch_bounds__(256)
void self_init(const float* __restrict__ M, const float* __restrict__ dinv,
               float* __restrict__ O, int n) {
    int idx = blockIdx.x * 256 + threadIdx.x;      // float4 index
    if (idx >= n * 32) return;
    int r = idx >> 5;
    float di = dinv[r];
    float c = di * di;
    float4 v = ((const float4*)M)[idx];
    v.x *= c; v.y *= c; v.z *= c; v.w *= c;
    ((float4*)O)[idx] = v;
}

// O[dst,:] += dinv[src]*dinv[dst] * M[src,:]  per edge. 32 lanes/edge, float4.
__global__ __launch_bounds__(256)
void scatter(const float* __restrict__ M, const int* __restrict__ ei,
             const float* __restrict__ dinv, float* __restrict__ O, int E_) {
    int g = threadIdx.x >> 5, lane = threadIdx.x & 31;
    int e = blockIdx.x * 8 + g;
    if (e >= E_) return;
    int s = ei[e], d = ei[E_ + e];
    float coef = dinv[s] * dinv[d];
    float4 v = *(const float4*)(M + (size_t)s * D_H + lane * 4);
    float* o = O + (size_t)d * D_H + lane * 4;
    atomicAdd(o + 0, v.x * coef);
    atomicAdd(o + 1, v.y * coef);
    atomicAdd(o + 2, v.z * coef);
    atomicAdd(o + 3, v.w * coef);
}

// column sums / sumsq over N rows -> stats[0:128]=sum, stats[128:256]=sumsq
__global__ __launch_bounds__(256)
void bn_stats(const float* __restrict__ H, float* __restrict__ stats, int n) {
    int tid = threadIdx.x;
    int col = tid & 127, half = tid >> 7;
    float s = 0.f, s2 = 0.f;
    for (int r = blockIdx.x * 2 + half; r < n; r += gridDim.x * 2) {
        float v = H[(size_t)r * 128 + col];
        s += v; s2 += v * v;
    }
    __shared__ float ls[256], ls2[256];
    ls[tid] = s; ls2[tid] = s2;
    __syncthreads();
    if (tid < 128) {
        s  = ls[tid]  + ls[tid + 128];
        s2 = ls2[tid] + ls2[tid + 128];
        atomicAdd(&stats[col], s);
        atomicAdd(&stats[128 + col], s2);
    }
}

// H = relu((H-mean)*rsqrt(var+eps)*gamma+beta), in place
__global__ __launch_bounds__(256)
void bn_apply(float* __restrict__ H, const float* __restrict__ stats,
              const float* __restrict__ gamma, const float* __restrict__ beta,
              int n) {
    int idx = blockIdx.x * 256 + threadIdx.x;      // float4 index
    if (idx >= n * 32) return;
    int c = (idx & 31) * 4;
    float inv_n = 1.0f / (float)n;
    float4 v = ((const float4*)H)[idx];
    float o[4] = {v.x, v.y, v.z, v.w};
    #pragma unroll
    for (int j = 0; j < 4; ++j) {
        float mean = stats[c + j] * inv_n;
        float var  = stats[128 + c + j] * inv_n - mean * mean;
        float sc   = rsqrtf(var + 1e-5f) * gamma[c + j];
        o[j] = fmaxf((o[j] - mean) * sc + beta[c + j], 0.f);
    }
    ((float4*)H)[idx] = make_float4(o[0], o[1], o[2], o[3]);
}

extern "C" void kernel_launch(void* const* d_in, const int* in_sizes, int n_in,
                              void* d_out, int out_size, void* d_ws, size_t ws_size,
                              hipStream_t stream) {
    const float* x    = (const float*)d_in[0];
    const int*   ei   = (const int*)d_in[1];
    const float* W0   = (const float*)d_in[2];
    const float* W1   = (const float*)d_in[3];
    const float* Wmu  = (const float*)d_in[4];
    const float* Wlog = (const float*)d_in[5];
    const float* g0   = (const float*)d_in[6];
    const float* b0   = (const float*)d_in[7];
    const float* g1   = (const float*)d_in[8];
    const float* b1   = (const float*)d_in[9];

    const int N_ = in_sizes[0] / 128;
    const int E_ = in_sizes[1] / 2;
    float* out = (float*)d_out;

    // workspace carve-up (256B aligned)
    char* w = (char*)d_ws;
    auto carve = [&](size_t bytes) {
        char* p = w;
        w += (bytes + 255) & ~(size_t)255;
        return p;
    };
    float* dinv  = (float*)carve((size_t)N_ * 4);
    int*   cnt   = (int*)  carve((size_t)N_ * 4);
    float* stats = (float*)carve(256 * 4);
    float* bufA  = (float*)carve((size_t)N_ * 128 * 4);
    float* bufB  = (float*)carve((size_t)N_ * 128 * 4);

    const int elem4  = N_ * 32;                  // float4 count of an N x 128 buf
    const int gElem  = (elem4 + 255) / 256;
    const int gGemm  = (N_ + 31) / 32;
    const int gScat  = (E_ + 7) / 8;

    // degree / dinv
    hipMemsetAsync(cnt, 0, (size_t)N_ * 4, stream);
    deg_count<<<(E_ + 255) / 256, 256, 0, stream>>>(ei, cnt, E_);
    make_dinv<<<(N_ + 255) / 256, 256, 0, stream>>>(cnt, dinv, N_);

    // ---- layer 0: h1 = relu(BN(Â (x @ W0))) ----
    gemm128<false><<<gGemm, 256, 0, stream>>>(x, W0, nullptr, bufA, nullptr, N_);
    self_init<<<gElem, 256, 0, stream>>>(bufA, dinv, bufB, N_);
    scatter<<<gScat, 256, 0, stream>>>(bufA, ei, dinv, bufB, E_);
    hipMemsetAsync(stats, 0, 256 * 4, stream);
    bn_stats<<<256, 256, 0, stream>>>(bufB, stats, N_);
    bn_apply<<<gElem, 256, 0, stream>>>(bufB, stats, g0, b0, N_);

    // ---- layer 1: h2 = relu(BN(Â (h1 @ W1))) ----
    gemm128<false><<<gGemm, 256, 0, stream>>>(bufB, W1, nullptr, bufA, nullptr, N_);
    self_init<<<gElem, 256, 0, stream>>>(bufA, dinv, bufB, N_);
    scatter<<<gScat, 256, 0, stream>>>(bufA, ei, dinv, bufB, E_);
    hipMemsetAsync(stats, 0, 256 * 4, stream);
    bn_stats<<<256, 256, 0, stream>>>(bufB, stats, N_);
    bn_apply<<<gElem, 256, 0, stream>>>(bufB, stats, g1, b1, N_);

    // ---- heads: a = Â h2 ; z_mean = a @ W_mu ; z_log_std = a @ W_logvar ----
    self_init<<<gElem, 256, 0, stream>>>(bufB, dinv, bufA, N_);
    scatter<<<gScat, 256, 0, stream>>>(bufB, ei, dinv, bufA, E_);
    gemm128<true><<<gGemm, 256, 0, stream>>>(bufA, Wmu, Wlog,
                                             out, out + (size_t)N_ * 64, N_);
}

// Round 2
// 620.678 us; speedup vs baseline: 6.8962x; 6.8962x over previous
//
#include <hip/hip_runtime.h>
#include <hip/hip_bf16.h>

// ---------------------------------------------------------------------------
// GCN-VGAE encoder, f32 end-to-end. Round 2: CSR gather instead of atomic
// scatter (scatter was 94% of runtime, atomic-latency-bound at 1.15% VALU).
//   deg/dinv -> CSR(rowptr, packed src+coef) ->
//   [GEMM -> gather(self fused) -> BN+ReLU] x2 -> gather -> split GEMM -> out
// ---------------------------------------------------------------------------

#define D_H 128

__global__ __launch_bounds__(256)
void deg_count(const int* __restrict__ ei, int* __restrict__ cnt, int E_) {
    int e = blockIdx.x * 256 + threadIdx.x;
    if (e < E_) atomicAdd(&cnt[ei[E_ + e]], 1);   // row 1 = dst
}

__global__ __launch_bounds__(256)
void make_dinv(const int* __restrict__ cnt, float* __restrict__ dinv, int n) {
    int i = blockIdx.x * 256 + threadIdx.x;
    if (i < n) dinv[i] = rsqrtf((float)cnt[i] + 1.0f);
}

// single-block exclusive scan of cnt[0..n) -> rowptr[0..n]
__global__ __launch_bounds__(1024)
void scan_rowptr(const int* __restrict__ cnt, int* __restrict__ rowptr, int n) {
    __shared__ int ls[1024];
    __shared__ int s_carry;
    const int tid = threadIdx.x;
    if (tid == 0) s_carry = 0;
    __syncthreads();
    for (int base = 0; base < n; base += 1024) {
        int i = base + tid;
        int v = (i < n) ? cnt[i] : 0;
        ls[tid] = v;
        __syncthreads();
        #pragma unroll
        for (int off = 1; off < 1024; off <<= 1) {
            int t = (tid >= off) ? ls[tid - off] : 0;
            __syncthreads();
            ls[tid] += t;
            __syncthreads();
        }
        int carry = s_carry;
        if (i < n) rowptr[i] = carry + ls[tid] - v;   // exclusive
        __syncthreads();
        if (tid == 0) s_carry = carry + ls[1023];
        __syncthreads();
    }
    if (tid == 0) rowptr[n] = s_carry;
}

// fill CSR: for edge (s,d) place packed (src, coef) at cursor[d]++
__global__ __launch_bounds__(256)
void csr_fill(const int* __restrict__ ei, const float* __restrict__ dinv,
              int* __restrict__ cursor, int2* __restrict__ csr_sw, int E_) {
    int e = blockIdx.x * 256 + threadIdx.x;
    if (e >= E_) return;
    int s = ei[e], d = ei[E_ + e];
    int p = atomicAdd(&cursor[d], 1);
    csr_sw[p] = make_int2(s, __float_as_int(dinv[s] * dinv[d]));
}

// Y = X @ W  (K=128). SPLIT: W = [Wa|Wb] (each 128x64), Ya/Yb are N x 64.
template<bool SPLIT>
__global__ __launch_bounds__(256)
void gemm128(const float* __restrict__ X, const float* __restrict__ Wa,
             const float* __restrict__ Wb, float* __restrict__ Ya,
             float* __restrict__ Yb, int nRows) {
    __shared__ float xs[32][128];
    const int tid = threadIdx.x;
    const int row0 = blockIdx.x * 32;

    #pragma unroll
    for (int q = 0; q < 4; ++q) {
        int flat = (q * 256 + tid) * 4;
        int r = flat >> 7, k = flat & 127;
        float4 v = make_float4(0.f, 0.f, 0.f, 0.f);
        if (row0 + r < nRows)
            v = *(const float4*)(X + (size_t)(row0 + r) * 128 + k);
        *(float4*)&xs[r][k] = v;
    }
    __syncthreads();

    const int tx = tid & 31, ty = tid >> 5;
    const int c0 = tx * 4, r0 = ty * 4;
    float acc[4][4] = {};

    for (int k = 0; k < 128; k += 4) {
        float xv[4][4];
        #pragma unroll
        for (int i = 0; i < 4; ++i)
            *(float4*)xv[i] = *(const float4*)&xs[r0 + i][k];
        #pragma unroll
        for (int j = 0; j < 4; ++j) {
            int kk = k + j;
            float4 wv;
            if (!SPLIT) {
                wv = *(const float4*)(Wa + kk * 128 + c0);
            } else {
                wv = (c0 < 64) ? *(const float4*)(Wa + kk * 64 + c0)
                               : *(const float4*)(Wb + kk * 64 + (c0 - 64));
            }
            #pragma unroll
            for (int i = 0; i < 4; ++i) {
                acc[i][0] += xv[i][j] * wv.x;
                acc[i][1] += xv[i][j] * wv.y;
                acc[i][2] += xv[i][j] * wv.z;
                acc[i][3] += xv[i][j] * wv.w;
            }
        }
    }

    #pragma unroll
    for (int i = 0; i < 4; ++i) {
        int r = row0 + r0 + i;
        if (r >= nRows) continue;
        float4 o = make_float4(acc[i][0], acc[i][1], acc[i][2], acc[i][3]);
        if (!SPLIT) {
            *(float4*)(Ya + (size_t)r * 128 + c0) = o;
        } else if (c0 < 64) {
            *(float4*)(Ya + (size_t)r * 64 + c0) = o;
        } else {
            *(float4*)(Yb + (size_t)r * 64 + (c0 - 64)) = o;
        }
    }
}

// O[d,:] = dinv[d]^2 * M[d,:] + sum_k coef_k * M[src_k,:]
// one wave (64 lanes) per dst row; lane owns channels {2*lane, 2*lane+1}
__global__ __launch_bounds__(256)
void gather(const float* __restrict__ M, const int* __restrict__ rowptr,
            const int2* __restrict__ csr_sw, const float* __restrict__ dinv,
            float* __restrict__ O, int n) {
    int wid  = (blockIdx.x * 256 + threadIdx.x) >> 6;
    int lane = threadIdx.x & 63;
    if (wid >= n) return;
    const float2* m2 = (const float2*)M;

    float di = dinv[wid];
    float c  = di * di;
    float2 v = m2[(size_t)wid * 64 + lane];
    float ax = v.x * c, ay = v.y * c;

    int beg = rowptr[wid], end = rowptr[wid + 1];
    for (int k = beg; k < end; ++k) {
        int2 sw = csr_sw[k];                       // wave-uniform broadcast
        float wv = __int_as_float(sw.y);
        float2 u = m2[(size_t)sw.x * 64 + lane];
        ax += wv * u.x;
        ay += wv * u.y;
    }
    ((float2*)O)[(size_t)wid * 64 + lane] = make_float2(ax, ay);
}

// column sums / sumsq over N rows -> stats[0:128]=sum, stats[128:256]=sumsq
__global__ __launch_bounds__(256)
void bn_stats(const float* __restrict__ H, float* __restrict__ stats, int n) {
    int tid = threadIdx.x;
    int col = tid & 127, half = tid >> 7;
    float s = 0.f, s2 = 0.f;
    for (int r = blockIdx.x * 2 + half; r < n; r += gridDim.x * 2) {
        float v = H[(size_t)r * 128 + col];
        s += v; s2 += v * v;
    }
    __shared__ float ls[256], ls2[256];
    ls[tid] = s; ls2[tid] = s2;
    __syncthreads();
    if (tid < 128) {
        s  = ls[tid]  + ls[tid + 128];
        s2 = ls2[tid] + ls2[tid + 128];
        atomicAdd(&stats[col], s);
        atomicAdd(&stats[128 + col], s2);
    }
}

__global__ __launch_bounds__(256)
void bn_apply(float* __restrict__ H, const float* __restrict__ stats,
              const float* __restrict__ gamma, const float* __restrict__ beta,
              int n) {
    int idx = blockIdx.x * 256 + threadIdx.x;      // float4 index
    if (idx >= n * 32) return;
    int c = (idx & 31) * 4;
    float inv_n = 1.0f / (float)n;
    float4 v = ((const float4*)H)[idx];
    float o[4] = {v.x, v.y, v.z, v.w};
    #pragma unroll
    for (int j = 0; j < 4; ++j) {
        float mean = stats[c + j] * inv_n;
        float var  = stats[128 + c + j] * inv_n - mean * mean;
        float sc   = rsqrtf(var + 1e-5f) * gamma[c + j];
        o[j] = fmaxf((o[j] - mean) * sc + beta[c + j], 0.f);
    }
    ((float4*)H)[idx] = make_float4(o[0], o[1], o[2], o[3]);
}

extern "C" void kernel_launch(void* const* d_in, const int* in_sizes, int n_in,
                              void* d_out, int out_size, void* d_ws, size_t ws_size,
                              hipStream_t stream) {
    const float* x    = (const float*)d_in[0];
    const int*   ei   = (const int*)d_in[1];
    const float* W0   = (const float*)d_in[2];
    const float* W1   = (const float*)d_in[3];
    const float* Wmu  = (const float*)d_in[4];
    const float* Wlog = (const float*)d_in[5];
    const float* g0   = (const float*)d_in[6];
    const float* b0   = (const float*)d_in[7];
    const float* g1   = (const float*)d_in[8];
    const float* b1   = (const float*)d_in[9];

    const int N_ = in_sizes[0] / 128;
    const int E_ = in_sizes[1] / 2;
    float* out = (float*)d_out;

    char* w = (char*)d_ws;
    auto carve = [&](size_t bytes) {
        char* p = w;
        w += (bytes + 255) & ~(size_t)255;
        return p;
    };
    float* dinv   = (float*)carve((size_t)N_ * 4);
    int*   cnt    = (int*)  carve((size_t)N_ * 4);
    int*   rowptr = (int*)  carve((size_t)(N_ + 1) * 4);
    int*   cursor = (int*)  carve((size_t)(N_ + 1) * 4);
    int2*  csr_sw = (int2*) carve((size_t)E_ * 8);
    float* stats  = (float*)carve(256 * 4);
    float* bufA   = (float*)carve((size_t)N_ * 128 * 4);
    float* bufB   = (float*)carve((size_t)N_ * 128 * 4);

    const int elem4 = N_ * 32;
    const int gElem = (elem4 + 255) / 256;
    const int gGemm = (N_ + 31) / 32;
    const int gGath = (N_ * 64 + 255) / 256;       // one wave per node

    // ---- graph preprocessing: dinv + CSR ----
    hipMemsetAsync(cnt, 0, (size_t)N_ * 4, stream);
    deg_count<<<(E_ + 255) / 256, 256, 0, stream>>>(ei, cnt, E_);
    make_dinv<<<(N_ + 255) / 256, 256, 0, stream>>>(cnt, dinv, N_);
    scan_rowptr<<<1, 1024, 0, stream>>>(cnt, rowptr, N_);
    hipMemcpyAsync(cursor, rowptr, (size_t)N_ * 4, hipMemcpyDeviceToDevice, stream);
    csr_fill<<<(E_ + 255) / 256, 256, 0, stream>>>(ei, dinv, cursor, csr_sw, E_);

    // ---- layer 0: h1 = relu(BN(Â (x @ W0))) ----
    gemm128<false><<<gGemm, 256, 0, stream>>>(x, W0, nullptr, bufA, nullptr, N_);
    gather<<<gGath, 256, 0, stream>>>(bufA, rowptr, csr_sw, dinv, bufB, N_);
    hipMemsetAsync(stats, 0, 256 * 4, stream);
    bn_stats<<<256, 256, 0, stream>>>(bufB, stats, N_);
    bn_apply<<<gElem, 256, 0, stream>>>(bufB, stats, g0, b0, N_);

    // ---- layer 1: h2 = relu(BN(Â (h1 @ W1))) ----
    gemm128<false><<<gGemm, 256, 0, stream>>>(bufB, W1, nullptr, bufA, nullptr, N_);
    gather<<<gGath, 256, 0, stream>>>(bufA, rowptr, csr_sw, dinv, bufB, N_);
    hipMemsetAsync(stats, 0, 256 * 4, stream);
    bn_stats<<<256, 256, 0, stream>>>(bufB, stats, N_);
    bn_apply<<<gElem, 256, 0, stream>>>(bufB, stats, g1, b1, N_);

    // ---- heads: a = Â h2 ; [z_mean | z_log_std] = a @ [W_mu | W_logvar] ----
    gather<<<gGath, 256, 0, stream>>>(bufB, rowptr, csr_sw, dinv, bufA, N_);
    gemm128<true><<<gGemm, 256, 0, stream>>>(bufA, Wmu, Wlog,
                                             out, out + (size_t)N_ * 64, N_);
}

// Round 3
// 467.159 us; speedup vs baseline: 9.1624x; 1.3286x over previous
//
#include <hip/hip_runtime.h>
#include <hip/hip_bf16.h>

// ---------------------------------------------------------------------------
// GCN-VGAE encoder, f32 end-to-end. Round 3:
//  - hierarchical rowptr scan (was: single-block scan at 89 us, 0.18% occ)
//  - gather: unroll x2 (2x MLP) + readfirstlane row bounds -> scalar loop
//   deg/dinv -> CSR(rowptr, packed src+coef) ->
//   [GEMM -> gather(self fused) -> BN+ReLU] x2 -> gather -> split GEMM -> out
// ---------------------------------------------------------------------------

#define D_H 128

__global__ __launch_bounds__(256)
void deg_count(const int* __restrict__ ei, int* __restrict__ cnt, int E_) {
    int e = blockIdx.x * 256 + threadIdx.x;
    if (e < E_) atomicAdd(&cnt[ei[E_ + e]], 1);   // row 1 = dst
}

__global__ __launch_bounds__(256)
void make_dinv(const int* __restrict__ cnt, float* __restrict__ dinv, int n) {
    int i = blockIdx.x * 256 + threadIdx.x;
    if (i < n) dinv[i] = rsqrtf((float)cnt[i] + 1.0f);
}

// ---- hierarchical exclusive scan: cnt[0..n) -> rowptr[0..n] ----
// phase 1: per-block (1024 elems) local exclusive scan + block totals
__global__ __launch_bounds__(1024)
void scan_blocks(const int* __restrict__ cnt, int* __restrict__ rowptr,
                 int* __restrict__ partials, int n) {
    __shared__ int ls[1024];
    int tid = threadIdx.x;
    int i = blockIdx.x * 1024 + tid;
    int v = (i < n) ? cnt[i] : 0;
    ls[tid] = v;
    __syncthreads();
    #pragma unroll
    for (int off = 1; off < 1024; off <<= 1) {
        int t = (tid >= off) ? ls[tid - off] : 0;
        __syncthreads();
        ls[tid] += t;
        __syncthreads();
    }
    if (i < n) rowptr[i] = ls[tid] - v;           // local exclusive
    if (tid == 1023) partials[blockIdx.x] = ls[1023];
}

// phase 2: single block scans the partials (nb <= 1024), writes grand total
__global__ __launch_bounds__(1024)
void scan_partials(int* __restrict__ partials, int* __restrict__ rowptr_n,
                   int nb) {
    __shared__ int ls[1024];
    int tid = threadIdx.x;
    int v = (tid < nb) ? partials[tid] : 0;
    ls[tid] = v;
    __syncthreads();
    #pragma unroll
    for (int off = 1; off < 1024; off <<= 1) {
        int t = (tid >= off) ? ls[tid - off] : 0;
        __syncthreads();
        ls[tid] += t;
        __syncthreads();
    }
    if (tid < nb) partials[tid] = ls[tid] - v;    // exclusive block offsets
    if (tid == 1023) *rowptr_n = ls[1023];        // rowptr[n] = total (= E)
}

// phase 3: add block offsets
__global__ __launch_bounds__(256)
void scan_add(int* __restrict__ rowptr, const int* __restrict__ partials, int n) {
    int i = blockIdx.x * 256 + threadIdx.x;
    if (i < n) rowptr[i] += partials[i >> 10];
}

// fill CSR: for edge (s,d) place packed (src, coef) at cursor[d]++
__global__ __launch_bounds__(256)
void csr_fill(const int* __restrict__ ei, const float* __restrict__ dinv,
              int* __restrict__ cursor, int2* __restrict__ csr_sw, int E_) {
    int e = blockIdx.x * 256 + threadIdx.x;
    if (e >= E_) return;
    int s = ei[e], d = ei[E_ + e];
    int p = atomicAdd(&cursor[d], 1);
    csr_sw[p] = make_int2(s, __float_as_int(dinv[s] * dinv[d]));
}

// Y = X @ W  (K=128). SPLIT: W = [Wa|Wb] (each 128x64), Ya/Yb are N x 64.
template<bool SPLIT>
__global__ __launch_bounds__(256)
void gemm128(const float* __restrict__ X, const float* __restrict__ Wa,
             const float* __restrict__ Wb, float* __restrict__ Ya,
             float* __restrict__ Yb, int nRows) {
    __shared__ float xs[32][128];
    const int tid = threadIdx.x;
    const int row0 = blockIdx.x * 32;

    #pragma unroll
    for (int q = 0; q < 4; ++q) {
        int flat = (q * 256 + tid) * 4;
        int r = flat >> 7, k = flat & 127;
        float4 v = make_float4(0.f, 0.f, 0.f, 0.f);
        if (row0 + r < nRows)
            v = *(const float4*)(X + (size_t)(row0 + r) * 128 + k);
        *(float4*)&xs[r][k] = v;
    }
    __syncthreads();

    const int tx = tid & 31, ty = tid >> 5;
    const int c0 = tx * 4, r0 = ty * 4;
    float acc[4][4] = {};

    for (int k = 0; k < 128; k += 4) {
        float xv[4][4];
        #pragma unroll
        for (int i = 0; i < 4; ++i)
            *(float4*)xv[i] = *(const float4*)&xs[r0 + i][k];
        #pragma unroll
        for (int j = 0; j < 4; ++j) {
            int kk = k + j;
            float4 wv;
            if (!SPLIT) {
                wv = *(const float4*)(Wa + kk * 128 + c0);
            } else {
                wv = (c0 < 64) ? *(const float4*)(Wa + kk * 64 + c0)
                               : *(const float4*)(Wb + kk * 64 + (c0 - 64));
            }
            #pragma unroll
            for (int i = 0; i < 4; ++i) {
                acc[i][0] += xv[i][j] * wv.x;
                acc[i][1] += xv[i][j] * wv.y;
                acc[i][2] += xv[i][j] * wv.z;
                acc[i][3] += xv[i][j] * wv.w;
            }
        }
    }

    #pragma unroll
    for (int i = 0; i < 4; ++i) {
        int r = row0 + r0 + i;
        if (r >= nRows) continue;
        float4 o = make_float4(acc[i][0], acc[i][1], acc[i][2], acc[i][3]);
        if (!SPLIT) {
            *(float4*)(Ya + (size_t)r * 128 + c0) = o;
        } else if (c0 < 64) {
            *(float4*)(Ya + (size_t)r * 64 + c0) = o;
        } else {
            *(float4*)(Yb + (size_t)r * 64 + (c0 - 64)) = o;
        }
    }
}

// O[d,:] = dinv[d]^2 * M[d,:] + sum_k coef_k * M[src_k,:]
// one wave per dst row; lane owns channels {2*lane, 2*lane+1}; unroll x2
__global__ __launch_bounds__(256)
void gather(const float* __restrict__ M, const int* __restrict__ rowptr,
            const int2* __restrict__ csr_sw, const float* __restrict__ dinv,
            float* __restrict__ O, int n) {
    int wid  = (blockIdx.x * 256 + threadIdx.x) >> 6;
    int lane = threadIdx.x & 63;
    if (wid >= n) return;
    const float2* m2 = (const float2*)M;

    float di = dinv[wid];
    float2 v = m2[(size_t)wid * 64 + lane];
    float ax = v.x * di * di, ay = v.y * di * di;
    float bx = 0.f, by = 0.f;

    // wid is wave-uniform -> hoist bounds to SGPRs (scalar loop, scalar meta addr)
    int beg = __builtin_amdgcn_readfirstlane(rowptr[wid]);
    int end = __builtin_amdgcn_readfirstlane(rowptr[wid + 1]);

    int k = beg;
    for (; k + 1 < end; k += 2) {
        int2 e0 = csr_sw[k], e1 = csr_sw[k + 1];
        float2 u0 = m2[(size_t)e0.x * 64 + lane];
        float2 u1 = m2[(size_t)e1.x * 64 + lane];
        float w0 = __int_as_float(e0.y), w1 = __int_as_float(e1.y);
        ax += w0 * u0.x; ay += w0 * u0.y;
        bx += w1 * u1.x; by += w1 * u1.y;
    }
    if (k < end) {
        int2 e0 = csr_sw[k];
        float2 u0 = m2[(size_t)e0.x * 64 + lane];
        float w0 = __int_as_float(e0.y);
        ax += w0 * u0.x; ay += w0 * u0.y;
    }
    ((float2*)O)[(size_t)wid * 64 + lane] = make_float2(ax + bx, ay + by);
}

// column sums / sumsq over N rows -> stats[0:128]=sum, stats[128:256]=sumsq
__global__ __launch_bounds__(256)
void bn_stats(const float* __restrict__ H, float* __restrict__ stats, int n) {
    int tid = threadIdx.x;
    int col = tid & 127, half = tid >> 7;
    float s = 0.f, s2 = 0.f;
    for (int r = blockIdx.x * 2 + half; r < n; r += gridDim.x * 2) {
        float v = H[(size_t)r * 128 + col];
        s += v; s2 += v * v;
    }
    __shared__ float ls[256], ls2[256];
    ls[tid] = s; ls2[tid] = s2;
    __syncthreads();
    if (tid < 128) {
        s  = ls[tid]  + ls[tid + 128];
        s2 = ls2[tid] + ls2[tid + 128];
        atomicAdd(&stats[col], s);
        atomicAdd(&stats[128 + col], s2);
    }
}

__global__ __launch_bounds__(256)
void bn_apply(float* __restrict__ H, const float* __restrict__ stats,
              const float* __restrict__ gamma, const float* __restrict__ beta,
              int n) {
    int idx = blockIdx.x * 256 + threadIdx.x;      // float4 index
    if (idx >= n * 32) return;
    int c = (idx & 31) * 4;
    float inv_n = 1.0f / (float)n;
    float4 v = ((const float4*)H)[idx];
    float o[4] = {v.x, v.y, v.z, v.w};
    #pragma unroll
    for (int j = 0; j < 4; ++j) {
        float mean = stats[c + j] * inv_n;
        float var  = stats[128 + c + j] * inv_n - mean * mean;
        float sc   = rsqrtf(var + 1e-5f) * gamma[c + j];
        o[j] = fmaxf((o[j] - mean) * sc + beta[c + j], 0.f);
    }
    ((float4*)H)[idx] = make_float4(o[0], o[1], o[2], o[3]);
}

extern "C" void kernel_launch(void* const* d_in, const int* in_sizes, int n_in,
                              void* d_out, int out_size, void* d_ws, size_t ws_size,
                              hipStream_t stream) {
    const float* x    = (const float*)d_in[0];
    const int*   ei   = (const int*)d_in[1];
    const float* W0   = (const float*)d_in[2];
    const float* W1   = (const float*)d_in[3];
    const float* Wmu  = (const float*)d_in[4];
    const float* Wlog = (const float*)d_in[5];
    const float* g0   = (const float*)d_in[6];
    const float* b0   = (const float*)d_in[7];
    const float* g1   = (const float*)d_in[8];
    const float* b1   = (const float*)d_in[9];

    const int N_ = in_sizes[0] / 128;
    const int E_ = in_sizes[1] / 2;
    float* out = (float*)d_out;

    char* w = (char*)d_ws;
    auto carve = [&](size_t bytes) {
        char* p = w;
        w += (bytes + 255) & ~(size_t)255;
        return p;
    };
    float* dinv   = (float*)carve((size_t)N_ * 4);
    int*   cnt    = (int*)  carve((size_t)N_ * 4);
    int*   rowptr = (int*)  carve((size_t)(N_ + 1) * 4);
    int*   cursor = (int*)  carve((size_t)(N_ + 1) * 4);
    int*   partials = (int*)carve(1024 * 4);
    int2*  csr_sw = (int2*) carve((size_t)E_ * 8);
    float* stats  = (float*)carve(256 * 4);
    float* bufA   = (float*)carve((size_t)N_ * 128 * 4);
    float* bufB   = (float*)carve((size_t)N_ * 128 * 4);

    const int elem4 = N_ * 32;
    const int gElem = (elem4 + 255) / 256;
    const int gGemm = (N_ + 31) / 32;
    const int gGath = (N_ * 64 + 255) / 256;       // one wave per node
    const int nb    = (N_ + 1023) / 1024;          // scan blocks (<=1024)

    // ---- graph preprocessing: dinv + CSR ----
    hipMemsetAsync(cnt, 0, (size_t)N_ * 4, stream);
    deg_count<<<(E_ + 255) / 256, 256, 0, stream>>>(ei, cnt, E_);
    make_dinv<<<(N_ + 255) / 256, 256, 0, stream>>>(cnt, dinv, N_);
    scan_blocks<<<nb, 1024, 0, stream>>>(cnt, rowptr, partials, N_);
    scan_partials<<<1, 1024, 0, stream>>>(partials, rowptr + N_, nb);
    scan_add<<<(N_ + 255) / 256, 256, 0, stream>>>(rowptr, partials, N_);
    hipMemcpyAsync(cursor, rowptr, (size_t)N_ * 4, hipMemcpyDeviceToDevice, stream);
    csr_fill<<<(E_ + 255) / 256, 256, 0, stream>>>(ei, dinv, cursor, csr_sw, E_);

    // ---- layer 0: h1 = relu(BN(Â (x @ W0))) ----
    gemm128<false><<<gGemm, 256, 0, stream>>>(x, W0, nullptr, bufA, nullptr, N_);
    gather<<<gGath, 256, 0, stream>>>(bufA, rowptr, csr_sw, dinv, bufB, N_);
    hipMemsetAsync(stats, 0, 256 * 4, stream);
    bn_stats<<<256, 256, 0, stream>>>(bufB, stats, N_);
    bn_apply<<<gElem, 256, 0, stream>>>(bufB, stats, g0, b0, N_);

    // ---- layer 1: h2 = relu(BN(Â (h1 @ W1))) ----
    gemm128<false><<<gGemm, 256, 0, stream>>>(bufB, W1, nullptr, bufA, nullptr, N_);
    gather<<<gGath, 256, 0, stream>>>(bufA, rowptr, csr_sw, dinv, bufB, N_);
    hipMemsetAsync(stats, 0, 256 * 4, stream);
    bn_stats<<<256, 256, 0, stream>>>(bufB, stats, N_);
    bn_apply<<<gElem, 256, 0, stream>>>(bufB, stats, g1, b1, N_);

    // ---- heads: a = Â h2 ; [z_mean | z_log_std] = a @ [W_mu | W_logvar] ----
    gather<<<gGath, 256, 0, stream>>>(bufB, rowptr, csr_sw, dinv, bufA, N_);
    gemm128<true><<<gGemm, 256, 0, stream>>>(bufA, Wmu, Wlog,
                                             out, out + (size_t)N_ * 64, N_);
}

// Round 4
// 363.269 us; speedup vs baseline: 11.7827x; 1.2860x over previous
//
#include <hip/hip_runtime.h>
#include <hip/hip_bf16.h>

// ---------------------------------------------------------------------------
// GCN-VGAE encoder. Round 4: bf16 aggregation payload (halves gather traffic,
// the dominant cost), BN-apply fused into consuming GEMM, head reordered to
// out = A^(h2 W) so the final gather writes d_out directly.
// Pipeline:
//   deg/dinv -> CSR ->
//   gemm0(x,W0)->Mbf  -> gather->Hf -> stats -> coef
//   gemm1(Hf bn+relu, W1)->Mbf -> gather->Hf -> stats -> coef
//   gemmH(Hf bn+relu, [Wmu|Wlog])->Mbf -> gather->d_out (split halves)
// ---------------------------------------------------------------------------

#define D_H 128

static __device__ __forceinline__ unsigned short f2bf(float f) {
    __hip_bfloat16 h = __float2bfloat16(f);
    return *reinterpret_cast<unsigned short*>(&h);
}
static __device__ __forceinline__ float bf_lo(unsigned int u) {
    return __uint_as_float(u << 16);
}
static __device__ __forceinline__ float bf_hi(unsigned int u) {
    return __uint_as_float(u & 0xffff0000u);
}

__global__ __launch_bounds__(256)
void deg_count(const int* __restrict__ ei, int* __restrict__ cnt, int E_) {
    int e = blockIdx.x * 256 + threadIdx.x;
    if (e < E_) atomicAdd(&cnt[ei[E_ + e]], 1);   // row 1 = dst
}

__global__ __launch_bounds__(256)
void make_dinv(const int* __restrict__ cnt, float* __restrict__ dinv, int n) {
    int i = blockIdx.x * 256 + threadIdx.x;
    if (i < n) dinv[i] = rsqrtf((float)cnt[i] + 1.0f);
}

// ---- hierarchical exclusive scan: cnt[0..n) -> rowptr[0..n] ----
__global__ __launch_bounds__(1024)
void scan_blocks(const int* __restrict__ cnt, int* __restrict__ rowptr,
                 int* __restrict__ partials, int n) {
    __shared__ int ls[1024];
    int tid = threadIdx.x;
    int i = blockIdx.x * 1024 + tid;
    int v = (i < n) ? cnt[i] : 0;
    ls[tid] = v;
    __syncthreads();
    #pragma unroll
    for (int off = 1; off < 1024; off <<= 1) {
        int t = (tid >= off) ? ls[tid - off] : 0;
        __syncthreads();
        ls[tid] += t;
        __syncthreads();
    }
    if (i < n) rowptr[i] = ls[tid] - v;           // local exclusive
    if (tid == 1023) partials[blockIdx.x] = ls[1023];
}

__global__ __launch_bounds__(1024)
void scan_partials(int* __restrict__ partials, int* __restrict__ rowptr_n,
                   int nb) {
    __shared__ int ls[1024];
    int tid = threadIdx.x;
    int v = (tid < nb) ? partials[tid] : 0;
    ls[tid] = v;
    __syncthreads();
    #pragma unroll
    for (int off = 1; off < 1024; off <<= 1) {
        int t = (tid >= off) ? ls[tid - off] : 0;
        __syncthreads();
        ls[tid] += t;
        __syncthreads();
    }
    if (tid < nb) partials[tid] = ls[tid] - v;    // exclusive block offsets
    if (tid == 1023) *rowptr_n = ls[1023];        // rowptr[n] = E
}

__global__ __launch_bounds__(256)
void scan_add(int* __restrict__ rowptr, const int* __restrict__ partials, int n) {
    int i = blockIdx.x * 256 + threadIdx.x;
    if (i < n) rowptr[i] += partials[i >> 10];
}

// fill CSR: for edge (s,d) place packed (src, coef) at cursor[d]++
__global__ __launch_bounds__(256)
void csr_fill(const int* __restrict__ ei, const float* __restrict__ dinv,
              int* __restrict__ cursor, int2* __restrict__ csr_sw, int E_) {
    int e = blockIdx.x * 256 + threadIdx.x;
    if (e >= E_) return;
    int s = ei[e], d = ei[E_ + e];
    int p = atomicAdd(&cursor[d], 1);
    csr_sw[p] = make_int2(s, __float_as_int(dinv[s] * dinv[d]));
}

// per-column BN coefficients: y = max(v*sc + sh, 0)
__global__ __launch_bounds__(128)
void bn_coef(const float* __restrict__ stats, const float* __restrict__ gamma,
             const float* __restrict__ beta, float* __restrict__ sc,
             float* __restrict__ sh, int n) {
    int c = threadIdx.x;
    float inv_n = 1.0f / (float)n;
    float mean = stats[c] * inv_n;
    float var  = stats[128 + c] * inv_n - mean * mean;
    float s = rsqrtf(var + 1e-5f) * gamma[c];
    sc[c] = s;
    sh[c] = beta[c] - mean * s;
}

// Y(bf16) = act(X) @ W, K=128, X f32. FUSE_BN: act = relu(v*sc+sh) else v.
// SPLIT_W: W = [Wa|Wb] col-concat (each 128x64) -> one 128-wide bf16 out.
template<bool FUSE_BN, bool SPLIT_W>
__global__ __launch_bounds__(256)
void gemm128(const float* __restrict__ X, const float* __restrict__ Wa,
             const float* __restrict__ Wb, const float* __restrict__ sc,
             const float* __restrict__ sh, unsigned short* __restrict__ Y,
             int nRows) {
    __shared__ float xs[32][128];
    const int tid = threadIdx.x;
    const int row0 = blockIdx.x * 32;

    #pragma unroll
    for (int q = 0; q < 4; ++q) {
        int flat = (q * 256 + tid) * 4;
        int r = flat >> 7, k = flat & 127;
        float4 v = make_float4(0.f, 0.f, 0.f, 0.f);
        if (row0 + r < nRows)
            v = *(const float4*)(X + (size_t)(row0 + r) * 128 + k);
        if (FUSE_BN) {
            float4 s4 = *(const float4*)(sc + k);
            float4 h4 = *(const float4*)(sh + k);
            v.x = fmaxf(v.x * s4.x + h4.x, 0.f);
            v.y = fmaxf(v.y * s4.y + h4.y, 0.f);
            v.z = fmaxf(v.z * s4.z + h4.z, 0.f);
            v.w = fmaxf(v.w * s4.w + h4.w, 0.f);
        }
        *(float4*)&xs[r][k] = v;
    }
    __syncthreads();

    const int tx = tid & 31, ty = tid >> 5;
    const int c0 = tx * 4, r0 = ty * 4;
    float acc[4][4] = {};

    for (int k = 0; k < 128; k += 4) {
        float xv[4][4];
        #pragma unroll
        for (int i = 0; i < 4; ++i)
            *(float4*)xv[i] = *(const float4*)&xs[r0 + i][k];
        #pragma unroll
        for (int j = 0; j < 4; ++j) {
            int kk = k + j;
            float4 wv;
            if (!SPLIT_W) {
                wv = *(const float4*)(Wa + kk * 128 + c0);
            } else {
                wv = (c0 < 64) ? *(const float4*)(Wa + kk * 64 + c0)
                               : *(const float4*)(Wb + kk * 64 + (c0 - 64));
            }
            #pragma unroll
            for (int i = 0; i < 4; ++i) {
                acc[i][0] += xv[i][j] * wv.x;
                acc[i][1] += xv[i][j] * wv.y;
                acc[i][2] += xv[i][j] * wv.z;
                acc[i][3] += xv[i][j] * wv.w;
            }
        }
    }

    #pragma unroll
    for (int i = 0; i < 4; ++i) {
        int r = row0 + r0 + i;
        if (r >= nRows) continue;
        ushort4 o;
        o.x = f2bf(acc[i][0]); o.y = f2bf(acc[i][1]);
        o.z = f2bf(acc[i][2]); o.w = f2bf(acc[i][3]);
        *(ushort4*)(Y + (size_t)r * 128 + c0) = o;
    }
}

// O[d,:] = dinv[d]^2 * M[d,:] + sum_k coef_k * M[src_k,:]   (M bf16)
// one wave per dst row; lane owns channels {2l, 2l+1}; unroll x4.
// TO_OUT: O laid out as [z_mean (N x 64) | z_log (N x 64)]; lanes<32 -> mean.
template<bool TO_OUT>
__global__ __launch_bounds__(256)
void gather_bf(const unsigned short* __restrict__ M,
               const int* __restrict__ rowptr, const int2* __restrict__ csr_sw,
               const float* __restrict__ dinv, float* __restrict__ O, int n) {
    int wid  = (blockIdx.x * 256 + threadIdx.x) >> 6;
    int lane = threadIdx.x & 63;
    if (wid >= n) return;
    const unsigned int* m2 = (const unsigned int*)M;   // 2 bf16 per uint

    float di = dinv[wid];
    unsigned int su = m2[(size_t)wid * 64 + lane];
    float c = di * di;
    float a0x = bf_lo(su) * c, a0y = bf_hi(su) * c;
    float a1x = 0.f, a1y = 0.f, a2x = 0.f, a2y = 0.f, a3x = 0.f, a3y = 0.f;

    int beg = __builtin_amdgcn_readfirstlane(rowptr[wid]);
    int end = __builtin_amdgcn_readfirstlane(rowptr[wid + 1]);

    int k = beg;
    for (; k + 3 < end; k += 4) {
        int2 e0 = csr_sw[k],     e1 = csr_sw[k + 1];
        int2 e2 = csr_sw[k + 2], e3 = csr_sw[k + 3];
        unsigned int u0 = m2[(size_t)e0.x * 64 + lane];
        unsigned int u1 = m2[(size_t)e1.x * 64 + lane];
        unsigned int u2 = m2[(size_t)e2.x * 64 + lane];
        unsigned int u3 = m2[(size_t)e3.x * 64 + lane];
        float w0 = __int_as_float(e0.y), w1 = __int_as_float(e1.y);
        float w2 = __int_as_float(e2.y), w3 = __int_as_float(e3.y);
        a0x += w0 * bf_lo(u0); a0y += w0 * bf_hi(u0);
        a1x += w1 * bf_lo(u1); a1y += w1 * bf_hi(u1);
        a2x += w2 * bf_lo(u2); a2y += w2 * bf_hi(u2);
        a3x += w3 * bf_lo(u3); a3y += w3 * bf_hi(u3);
    }
    for (; k < end; ++k) {
        int2 e0 = csr_sw[k];
        unsigned int u0 = m2[(size_t)e0.x * 64 + lane];
        float w0 = __int_as_float(e0.y);
        a0x += w0 * bf_lo(u0); a0y += w0 * bf_hi(u0);
    }
    float ax = (a0x + a1x) + (a2x + a3x);
    float ay = (a0y + a1y) + (a2y + a3y);

    if (!TO_OUT) {
        ((float2*)O)[(size_t)wid * 64 + lane] = make_float2(ax, ay);
    } else {
        float* dst = (lane < 32)
            ? O + (size_t)wid * 64 + 2 * lane
            : O + (size_t)n * 64 + (size_t)wid * 64 + 2 * (lane - 32);
        *(float2*)dst = make_float2(ax, ay);
    }
}

// column sums / sumsq over N rows -> stats[0:128]=sum, stats[128:256]=sumsq
__global__ __launch_bounds__(256)
void bn_stats(const float* __restrict__ H, float* __restrict__ stats, int n) {
    int tid = threadIdx.x;
    int col = tid & 127, half = tid >> 7;
    float s = 0.f, s2 = 0.f;
    for (int r = blockIdx.x * 2 + half; r < n; r += gridDim.x * 2) {
        float v = H[(size_t)r * 128 + col];
        s += v; s2 += v * v;
    }
    __shared__ float ls[256], ls2[256];
    ls[tid] = s; ls2[tid] = s2;
    __syncthreads();
    if (tid < 128) {
        s  = ls[tid]  + ls[tid + 128];
        s2 = ls2[tid] + ls2[tid + 128];
        atomicAdd(&stats[col], s);
        atomicAdd(&stats[128 + col], s2);
    }
}

extern "C" void kernel_launch(void* const* d_in, const int* in_sizes, int n_in,
                              void* d_out, int out_size, void* d_ws, size_t ws_size,
                              hipStream_t stream) {
    const float* x    = (const float*)d_in[0];
    const int*   ei   = (const int*)d_in[1];
    const float* W0   = (const float*)d_in[2];
    const float* W1   = (const float*)d_in[3];
    const float* Wmu  = (const float*)d_in[4];
    const float* Wlog = (const float*)d_in[5];
    const float* g0   = (const float*)d_in[6];
    const float* b0   = (const float*)d_in[7];
    const float* g1   = (const float*)d_in[8];
    const float* b1   = (const float*)d_in[9];

    const int N_ = in_sizes[0] / 128;
    const int E_ = in_sizes[1] / 2;
    float* out = (float*)d_out;

    char* w = (char*)d_ws;
    auto carve = [&](size_t bytes) {
        char* p = w;
        w += (bytes + 255) & ~(size_t)255;
        return p;
    };
    float* dinv   = (float*)carve((size_t)N_ * 4);
    int*   cnt    = (int*)  carve((size_t)N_ * 4);
    int*   rowptr = (int*)  carve((size_t)(N_ + 1) * 4);
    int*   cursor = (int*)  carve((size_t)(N_ + 1) * 4);
    int*   partials = (int*)carve(1024 * 4);
    int2*  csr_sw = (int2*) carve((size_t)E_ * 8);
    float* stats0 = (float*)carve(256 * 4);
    float* stats1 = (float*)carve(256 * 4);
    float* sc0    = (float*)carve(128 * 4);
    float* sh0    = (float*)carve(128 * 4);
    float* sc1    = (float*)carve(128 * 4);
    float* sh1    = (float*)carve(128 * 4);
    unsigned short* Mbf = (unsigned short*)carve((size_t)N_ * 128 * 2);
    float* Hf     = (float*)carve((size_t)N_ * 128 * 4);

    const int gGemm = (N_ + 31) / 32;
    const int gGath = (N_ * 64 + 255) / 256;       // one wave per node
    const int nb    = (N_ + 1023) / 1024;

    // ---- graph preprocessing: dinv + CSR ----
    hipMemsetAsync(cnt, 0, (size_t)N_ * 4, stream);
    deg_count<<<(E_ + 255) / 256, 256, 0, stream>>>(ei, cnt, E_);
    make_dinv<<<(N_ + 255) / 256, 256, 0, stream>>>(cnt, dinv, N_);
    scan_blocks<<<nb, 1024, 0, stream>>>(cnt, rowptr, partials, N_);
    scan_partials<<<1, 1024, 0, stream>>>(partials, rowptr + N_, nb);
    scan_add<<<(N_ + 255) / 256, 256, 0, stream>>>(rowptr, partials, N_);
    hipMemcpyAsync(cursor, rowptr, (size_t)N_ * 4, hipMemcpyDeviceToDevice, stream);
    csr_fill<<<(E_ + 255) / 256, 256, 0, stream>>>(ei, dinv, cursor, csr_sw, E_);

    // ---- layer 0 ----
    gemm128<false, false><<<gGemm, 256, 0, stream>>>(x, W0, nullptr, nullptr,
                                                     nullptr, Mbf, N_);
    gather_bf<false><<<gGath, 256, 0, stream>>>(Mbf, rowptr, csr_sw, dinv, Hf, N_);
    hipMemsetAsync(stats0, 0, 256 * 4, stream);
    bn_stats<<<256, 256, 0, stream>>>(Hf, stats0, N_);
    bn_coef<<<1, 128, 0, stream>>>(stats0, g0, b0, sc0, sh0, N_);

    // ---- layer 1 (BN0+ReLU fused into GEMM load) ----
    gemm128<true, false><<<gGemm, 256, 0, stream>>>(Hf, W1, nullptr, sc0, sh0,
                                                    Mbf, N_);
    gather_bf<false><<<gGath, 256, 0, stream>>>(Mbf, rowptr, csr_sw, dinv, Hf, N_);
    hipMemsetAsync(stats1, 0, 256 * 4, stream);
    bn_stats<<<256, 256, 0, stream>>>(Hf, stats1, N_);
    bn_coef<<<1, 128, 0, stream>>>(stats1, g1, b1, sc1, sh1, N_);

    // ---- heads (BN1+ReLU fused): Mh = relu(BN(Hf)) @ [Wmu|Wlog]; out = A^ Mh
    gemm128<true, true><<<gGemm, 256, 0, stream>>>(Hf, Wmu, Wlog, sc1, sh1,
                                                   Mbf, N_);
    gather_bf<true><<<gGath, 256, 0, stream>>>(Mbf, rowptr, csr_sw, dinv, out, N_);
}